// Round 3
// baseline (431.986 us; speedup 1.0000x reference)
//
#include <hip/hip_runtime.h>
#include <stdint.h>

#define CIN 256
#define PIX 32768
#define MTOT 1152
#define NCOUT 128
#define OHW 129

typedef unsigned short ushort_t;
typedef __attribute__((ext_vector_type(8))) short short8;
typedef __attribute__((ext_vector_type(4))) float f32x4;

__device__ __forceinline__ float b2f(ushort_t u){
  union { unsigned int i; float f; } v; v.i = ((unsigned int)u) << 16; return v.f;
}
__device__ __forceinline__ ushort_t f2b(float f){
  union { float f; unsigned int i; } v; v.f = f;
  unsigned int i = v.i;
  unsigned int r = (i + 0x7FFFu + ((i >> 16) & 1u)) >> 16;
  return (ushort_t)r;
}

// ------------- Kernel D: detect input dtype (bf16 vs fp32) -------------------
__global__ __launch_bounds__(256) void k_detect(const ushort_t* __restrict__ x,
                                                float* __restrict__ flag){
  __shared__ float red[256];
  int t = threadIdx.x;
  float mx = 0.f;
  for (int i = t; i < 65536; i += 256){
    float f = fabsf(b2f(x[i]));
    if (!(f < 1e30f)) f = 1e30f;       // NaN/Inf patterns count as huge
    mx = fmaxf(mx, f);
  }
  red[t] = mx; __syncthreads();
  for (int s = 128; s > 0; s >>= 1){
    if (t < s) red[t] = fmaxf(red[t], red[t+s]);
    __syncthreads();
  }
  if (t == 0) flag[0] = (red[0] < 1e10f) ? 1.0f : 0.0f;  // 1 -> bf16
}

// ------------- Kernel 0: x -> xT[pix][ci] (bf16), lam[pix], zero vn2 ---------
__global__ __launch_bounds__(256) void k_prep_pix(const void* __restrict__ xraw,
                                                  const float* __restrict__ flag,
                                                  ushort_t* __restrict__ xT,
                                                  float* __restrict__ lam,
                                                  float* __restrict__ vn2){
  __shared__ float tile[64*129];
  __shared__ float ssum[256];
  int isb = (flag[0] != 0.0f);
  int t = threadIdx.x;
  int p0 = blockIdx.x * 128;
  int b = p0 >> 12;
  int hw0 = p0 & 4095;
  float s = 0.f;
  for (int ci0 = 0; ci0 < 256; ci0 += 64){
    __syncthreads();
    if (isb){
      const ushort_t* xb = (const ushort_t*)xraw + ((size_t)b*CIN)*4096 + hw0;
#pragma unroll
      for (int i = 0; i < 32; ++i){
        int idx = i*256 + t;
        int ch = idx >> 7, p = idx & 127;
        tile[ch*129 + p] = b2f(xb[(size_t)(ci0+ch)*4096 + p]);
      }
    } else {
      const float* xb = (const float*)xraw + ((size_t)b*CIN)*4096 + hw0;
#pragma unroll
      for (int i = 0; i < 32; ++i){
        int idx = i*256 + t;
        int ch = idx >> 7, p = idx & 127;
        tile[ch*129 + p] = xb[(size_t)(ci0+ch)*4096 + p];
      }
    }
    __syncthreads();
    int p = t & 127, cih = t >> 7;
    __align__(16) ushort_t buf[32];
#pragma unroll
    for (int i = 0; i < 32; ++i){
      float f = tile[(cih*32+i)*129 + p];
      buf[i] = f2b(f);
      s += f*f;
    }
    uint4* dst = (uint4*)(xT + (size_t)(p0+p)*256 + ci0 + cih*32);
#pragma unroll
    for (int q = 0; q < 4; ++q) dst[q] = *(uint4*)&buf[q*8];
  }
  ssum[t] = s;
  __syncthreads();
  if (t < 128){
    float n2 = ssum[t] + ssum[t+128];
    lam[p0+t] = 2.0f / (1.0f - n2);   // c = 1
    vn2[p0+t] = 0.f;
  }
}

// ------------- Kernel 1: zT[m][ci] (bf16), per-column constants --------------
__global__ __launch_bounds__(256) void k_prep_col(const void* __restrict__ zraw,
                                                  const void* __restrict__ rraw,
                                                  const float* __restrict__ flag,
                                                  ushort_t* __restrict__ zT,
                                                  float* __restrict__ A1,
                                                  float* __restrict__ B1,
                                                  float* __restrict__ S1){
  int isb = (flag[0] != 0.0f);
  int m = blockIdx.x*256 + threadIdx.x;
  if (m >= MTOT) return;
  float s = 0.f;
  for (int c0 = 0; c0 < 256; c0 += 32){
    __align__(16) ushort_t buf[32];
#pragma unroll
    for (int i = 0; i < 32; ++i){
      float f = isb ? b2f(((const ushort_t*)zraw)[(size_t)(c0+i)*MTOT + m])
                    : ((const float*)zraw)[(size_t)(c0+i)*MTOT + m];
      buf[i] = f2b(f); s += f*f;
    }
    uint4* dst = (uint4*)(zT + (size_t)m*256 + c0);
#pragma unroll
    for (int q = 0; q < 4; ++q) dst[q] = *(uint4*)&buf[q*8];
  }
  float zn = fmaxf(sqrtf(s), 1e-15f);
  float rv = isb ? b2f(((const ushort_t*)rraw)[m]) : ((const float*)rraw)[m];
  float tc = 2.0f * rv;               // tcr = 2*sqrt(c)*r, c=1
  A1[m] = coshf(tc) / zn;
  B1[m] = sinhf(tc);
  S1[m] = 2.0f * zn;
}

// ------------- Kernel 2: GEMM + asinh epilogue -> v (bf16), vn2 atomics ------
__global__ __launch_bounds__(256) void k_gemm(const ushort_t* __restrict__ xT,
                                              const ushort_t* __restrict__ zT,
                                              const float* __restrict__ lam,
                                              const float* __restrict__ A1,
                                              const float* __restrict__ B1,
                                              const float* __restrict__ S1,
                                              ushort_t* __restrict__ vbuf,
                                              float* __restrict__ vn2){
  __shared__ ushort_t sh[16384];   // As [0,8192), Bs [8192,16384); epilogue vtile
  __shared__ float lamS[128], A1S[128], B1S[128], S1S[128];
  int t = threadIdx.x;
  int p0 = blockIdx.x * 128;
  int n0 = blockIdx.y * 128;
  if (t < 128){
    lamS[t] = lam[p0+t];
    A1S[t] = A1[n0+t]; B1S[t] = B1[n0+t]; S1S[t] = S1[n0+t];
  }
  int wave = t >> 6, lane = t & 63;
  int wr = wave >> 1, wc = wave & 1;
  f32x4 acc[4][4];
#pragma unroll
  for (int i=0;i<4;i++)
#pragma unroll
    for (int j=0;j<4;j++) acc[i][j] = (f32x4){0.f,0.f,0.f,0.f};

  for (int kt = 0; kt < 4; ++kt){
    int ci0 = kt*64;
    __syncthreads();
    // explicit staging: 1024 chunks of 8 bf16 each for A and for B
#pragma unroll
    for (int i = 0; i < 4; ++i){
      int c = i*256 + t;
      int p = c >> 3, ko = (c & 7)*8;
      *(uint4*)&sh[c*8] = *(const uint4*)(xT + (size_t)(p0+p)*256 + ci0 + ko);
    }
#pragma unroll
    for (int i = 0; i < 4; ++i){
      int c = i*256 + t;
      int mrow = c >> 3, ko = (c & 7)*8;
      *(uint4*)&sh[8192 + c*8] = *(const uint4*)(zT + (size_t)(n0+mrow)*256 + ci0 + ko);
    }
    __syncthreads();
#pragma unroll
    for (int ks = 0; ks < 2; ++ks){
      short8 av[4], bv[4];
      int koff = ks*32 + (lane>>4)*8;
#pragma unroll
      for (int rt = 0; rt < 4; ++rt){
        int row = wr*64 + rt*16 + (lane & 15);
        av[rt] = *(const short8*)&sh[row*64 + koff];
      }
#pragma unroll
      for (int ct = 0; ct < 4; ++ct){
        int mr = wc*64 + ct*16 + (lane & 15);
        bv[ct] = *(const short8*)&sh[8192 + mr*64 + koff];
      }
#pragma unroll
      for (int rt = 0; rt < 4; ++rt)
#pragma unroll
        for (int ct = 0; ct < 4; ++ct)
          acc[rt][ct] = __builtin_amdgcn_mfma_f32_16x16x32_bf16(av[rt], bv[ct], acc[rt][ct], 0, 0, 0);
    }
  }
  __syncthreads();
  // epilogue: v = S1*asinh(lam*xz*A1 - (lam-1)*B1); stage LDS vtile[128][128] bf16
#pragma unroll
  for (int rt = 0; rt < 4; ++rt){
#pragma unroll
    for (int ct = 0; ct < 4; ++ct){
#pragma unroll
      for (int rg = 0; rg < 4; ++rg){
        int row = wr*64 + rt*16 + (lane>>4)*4 + rg;
        int col = wc*64 + ct*16 + (lane & 15);
        float xz = acc[rt][ct][rg];
        float lm = lamS[row];
        float tv = lm * xz * A1S[col] - (lm - 1.0f) * B1S[col];
        float v = S1S[col] * asinhf(tv);
        sh[row*128 + col] = f2b(v);
      }
    }
  }
  __syncthreads();
  {
    // each thread flushes one 64-col half-row: 64 bf16 = 128 B = 8 uint4
    int row = t >> 1, half = t & 1;
    float s = 0.f;
    uint4 outv[8];
#pragma unroll
    for (int i = 0; i < 8; ++i){
      ushort_t* src = &sh[row*128 + half*64 + i*8];
      uint4 u = *(uint4*)src;
      outv[i] = u;
#pragma unroll
      for (int e = 0; e < 8; ++e){ float f = b2f(src[e]); s += f*f; }
    }
    uint4* dst = (uint4*)(vbuf + (size_t)(p0+row)*MTOT + n0 + half*64);
#pragma unroll
    for (int i = 0; i < 8; ++i) dst[i] = outv[i];
    atomicAdd(&vn2[p0+row], s);
  }
}

// ------------- Kernel 3: in-place repack v -> num[pix][k][cout], den ---------
__global__ __launch_bounds__(256) void k_repack(ushort_t* __restrict__ vbuf,
                                                const float* __restrict__ vn2,
                                                float* __restrict__ den){
  __shared__ float part[4][9];
  int t = threadIdx.x;
  int slot = t >> 7;          // pixel slot 0/1
  int c = t & 127;            // cout
  int wave = t >> 6;
  size_t pix = (size_t)blockIdx.x*2 + slot;
  float inv = 1.0f / (1.0f + sqrtf(1.0f + vn2[pix]));   // c = 1
  const ushort_t* bp = vbuf + pix*MTOT + c*9;
  float w[9];
#pragma unroll
  for (int k = 0; k < 9; ++k) w[k] = b2f(bp[k]) * inv;
  float sq[9];
#pragma unroll
  for (int k = 0; k < 9; ++k) sq[k] = w[k]*w[k];
#pragma unroll
  for (int d = 1; d < 64; d <<= 1){
#pragma unroll
    for (int k = 0; k < 9; ++k) sq[k] += __shfl_xor(sq[k], d, 64);
  }
  if ((t & 63) == 0){
#pragma unroll
    for (int k = 0; k < 9; ++k) part[wave][k] = sq[k];
  }
  __syncthreads();
  float lam2[9];
#pragma unroll
  for (int k = 0; k < 9; ++k){
    float S = part[slot*2][k] + part[slot*2+1][k];
    lam2[k] = 2.0f / (1.0f - S);
  }
  ushort_t* wp = vbuf + pix*MTOT;
#pragma unroll
  for (int k = 0; k < 9; ++k) wp[k*128 + c] = f2b(lam2[k]*w[k]);
  if (c < 9) den[pix*9 + c] = lam2[c] - 1.0f;
}

// ------------- Kernel 4: gather fold + gyromidpoint + Mobius 1/2 -------------
__global__ __launch_bounds__(1024) void k_fold(const ushort_t* __restrict__ vbuf,
                                               const float* __restrict__ den,
                                               const float* __restrict__ flag,
                                               void* __restrict__ outraw){
  __shared__ ushort_t stg[128*32];
  int isb = (flag[0] != 0.0f);
  int t = threadIdx.x;
  int oy = blockIdx.y;
  int bz = blockIdx.z;
  int wv = t >> 6, l = t & 63, half = l >> 5, cl = l & 31;
  int ox = blockIdx.x*32 + wv*2 + half;
  int oxc = min(ox, 128);
  int khs[2], hs[2], kws[2], wxs[2];
  int ny = 0, nx = 0;
  if (oy & 1){ khs[0]=1; hs[0]=(oy-1)>>1; ny=1; }
  else {
    int h0 = oy>>1; if (h0 < 64){ khs[ny]=0; hs[ny]=h0; ny++; }
    if (oy >= 2){ khs[ny]=2; hs[ny]=(oy-2)>>1; ny++; }
  }
  if (oxc & 1){ kws[0]=1; wxs[0]=(oxc-1)>>1; nx=1; }
  else {
    int w0 = oxc>>1; if (w0 < 64){ kws[nx]=0; wxs[nx]=w0; nx++; }
    if (oxc >= 2){ kws[nx]=2; wxs[nx]=(oxc-2)>>1; nx++; }
  }
  float num[4] = {0,0,0,0};
  float dacc = 0.f;
  for (int iy = 0; iy < ny; ++iy){
    for (int ix = 0; ix < nx; ++ix){
      int pix = (bz<<12) + (hs[iy]<<6) + wxs[ix];
      int k = khs[iy]*3 + kws[ix];
      const ushort_t* bp = vbuf + (size_t)pix*MTOT + k*128;
      dacc += den[(size_t)pix*9 + k];
#pragma unroll
      for (int j = 0; j < 4; ++j) num[j] += b2f(bp[cl + 32*j]);
    }
  }
  float fr[4], fn2 = 0.f;
  float dinv = 1.0f / dacc;
#pragma unroll
  for (int j = 0; j < 4; ++j){ fr[j] = num[j]*dinv; fn2 += fr[j]*fr[j]; }
#pragma unroll
  for (int d = 1; d < 32; d <<= 1) fn2 += __shfl_xor(fn2, d, 32);
  float fn = sqrtf(fn2);
  float arg = fminf(fn, 1.0f - 1e-7f);
  // tanh(0.5*atanh(arg)) = arg/(1+sqrt(1-arg^2))
  float scale = arg / ((1.0f + sqrtf(1.0f - arg*arg)) * fmaxf(fn, 1e-15f));
  int oxl = wv*2 + half;
#pragma unroll
  for (int j = 0; j < 4; ++j) stg[(cl + 32*j)*32 + oxl] = f2b(fr[j]*scale);
  __syncthreads();
  int c = t >> 3, x4 = (t & 7)*4;
#pragma unroll
  for (int e = 0; e < 4; ++e){
    int oxw = blockIdx.x*32 + x4 + e;
    if (oxw < OHW){
      size_t off = (((size_t)bz*NCOUT + c)*OHW + oy)*OHW + oxw;
      if (isb) ((ushort_t*)outraw)[off] = stg[c*32 + x4 + e];
      else     ((float*)outraw)[off]    = b2f(stg[c*32 + x4 + e]);
    }
  }
}

// ------------- launch --------------------------------------------------------
extern "C" void kernel_launch(void* const* d_in, const int* in_sizes, int n_in,
                              void* d_out, int out_size, void* d_ws, size_t ws_size,
                              hipStream_t stream){
  const void* x = d_in[0];
  const void* z = d_in[1];
  const void* r = d_in[2];
  char* ws = (char*)d_ws;
  size_t off = 0;
  auto alloc = [&](size_t bytes)->char*{ char* p = ws + off; off += (bytes + 255) & ~(size_t)255; return p; };
  ushort_t* xT  = (ushort_t*)alloc((size_t)PIX*CIN*2);
  ushort_t* zT  = (ushort_t*)alloc((size_t)MTOT*CIN*2);
  float* lam    = (float*)alloc((size_t)PIX*4);
  float* vn2    = (float*)alloc((size_t)PIX*4);
  float* A1     = (float*)alloc(MTOT*4);
  float* B1     = (float*)alloc(MTOT*4);
  float* S1     = (float*)alloc(MTOT*4);
  ushort_t* vbuf= (ushort_t*)alloc((size_t)PIX*MTOT*2);
  float* den    = (float*)alloc((size_t)PIX*9*4);
  float* flag   = (float*)alloc(256);
  (void)in_sizes; (void)n_in; (void)out_size; (void)ws_size;

  hipLaunchKernelGGL(k_detect,   dim3(1),       dim3(256),  0, stream, (const ushort_t*)x, flag);
  hipLaunchKernelGGL(k_prep_pix, dim3(256),     dim3(256),  0, stream, x, flag, xT, lam, vn2);
  hipLaunchKernelGGL(k_prep_col, dim3(5),       dim3(256),  0, stream, z, r, flag, zT, A1, B1, S1);
  hipLaunchKernelGGL(k_gemm,     dim3(256,9),   dim3(256),  0, stream, xT, zT, lam, A1, B1, S1, vbuf, vn2);
  hipLaunchKernelGGL(k_repack,   dim3(16384),   dim3(256),  0, stream, vbuf, vn2, den);
  hipLaunchKernelGGL(k_fold,     dim3(5,129,8), dim3(1024), 0, stream, vbuf, den, flag, d_out);
}

// Round 4
// 354.470 us; speedup vs baseline: 1.2187x; 1.2187x over previous
//
#include <hip/hip_runtime.h>
#include <stdint.h>

#define CIN 256
#define PIX 32768
#define MTOT 1152
#define NCOUT 128
#define OHW 129

typedef unsigned short ushort_t;
typedef __attribute__((ext_vector_type(8))) short short8;
typedef __attribute__((ext_vector_type(4))) float f32x4;

__device__ __forceinline__ float b2f(ushort_t u){
  union { unsigned int i; float f; } v; v.i = ((unsigned int)u) << 16; return v.f;
}
__device__ __forceinline__ ushort_t f2b(float f){
  union { float f; unsigned int i; } v; v.f = f;
  unsigned int i = v.i;
  unsigned int r = (i + 0x7FFFu + ((i >> 16) & 1u)) >> 16;
  return (ushort_t)r;
}

// ------------- Kernel D: detect input dtype (bf16 vs fp32) -------------------
__global__ __launch_bounds__(256) void k_detect(const ushort_t* __restrict__ x,
                                                float* __restrict__ flag){
  __shared__ float red[256];
  int t = threadIdx.x;
  float mx = 0.f;
  for (int i = t; i < 65536; i += 256){
    float f = fabsf(b2f(x[i]));
    if (!(f < 1e30f)) f = 1e30f;       // NaN/Inf patterns count as huge
    mx = fmaxf(mx, f);
  }
  red[t] = mx; __syncthreads();
  for (int s = 128; s > 0; s >>= 1){
    if (t < s) red[t] = fmaxf(red[t], red[t+s]);
    __syncthreads();
  }
  if (t == 0) flag[0] = (red[0] < 1e10f) ? 1.0f : 0.0f;  // 1 -> bf16
}

// ------------- Kernel 0: x -> xT[pix][ci] (bf16), lam[pix], zero vn2 ---------
__global__ __launch_bounds__(256) void k_prep_pix(const void* __restrict__ xraw,
                                                  const float* __restrict__ flag,
                                                  ushort_t* __restrict__ xT,
                                                  float* __restrict__ lam,
                                                  float* __restrict__ vn2){
  __shared__ float tile[64*129];
  __shared__ float ssum[256];
  int isb = (flag[0] != 0.0f);
  int t = threadIdx.x;
  int p0 = blockIdx.x * 128;
  int b = p0 >> 12;
  int hw0 = p0 & 4095;
  float s = 0.f;
  for (int ci0 = 0; ci0 < 256; ci0 += 64){
    __syncthreads();
    if (isb){
      const uint* xb32 = (const uint*)((const ushort_t*)xraw + ((size_t)b*CIN)*4096 + hw0);
#pragma unroll
      for (int i = 0; i < 16; ++i){
        int idx = i*256 + t;          // 0..4095 uint chunks
        int ch = idx >> 6;            // 0..63
        int pp = idx & 63;            // uint column
        uint u = xb32[(size_t)(ci0+ch)*2048 + pp];
        tile[ch*129 + pp*2]     = b2f((ushort_t)(u & 0xffffu));
        tile[ch*129 + pp*2 + 1] = b2f((ushort_t)(u >> 16));
      }
    } else {
      const float* xb = (const float*)xraw + ((size_t)b*CIN)*4096 + hw0;
#pragma unroll
      for (int i = 0; i < 32; ++i){
        int idx = i*256 + t;
        int ch = idx >> 7, p = idx & 127;
        tile[ch*129 + p] = xb[(size_t)(ci0+ch)*4096 + p];
      }
    }
    __syncthreads();
    int p = t & 127, cih = t >> 7;
    __align__(16) ushort_t buf[32];
#pragma unroll
    for (int i = 0; i < 32; ++i){
      float f = tile[(cih*32+i)*129 + p];
      buf[i] = f2b(f);
      s += f*f;
    }
    uint4* dst = (uint4*)(xT + (size_t)(p0+p)*256 + ci0 + cih*32);
#pragma unroll
    for (int q = 0; q < 4; ++q) dst[q] = *(uint4*)&buf[q*8];
  }
  ssum[t] = s;
  __syncthreads();
  if (t < 128){
    float n2 = ssum[t] + ssum[t+128];
    lam[p0+t] = 2.0f / (1.0f - n2);   // c = 1
    vn2[p0+t] = 0.f;
  }
}

// ------------- Kernel 1: PERMUTED zT[n][ci], per-column constants ------------
// column order n = k*128 + c  <->  reference m = c*9 + k
__global__ __launch_bounds__(256) void k_prep_col(const void* __restrict__ zraw,
                                                  const void* __restrict__ rraw,
                                                  const float* __restrict__ flag,
                                                  ushort_t* __restrict__ zT,
                                                  float* __restrict__ A1,
                                                  float* __restrict__ B1,
                                                  float* __restrict__ S1){
  int isb = (flag[0] != 0.0f);
  int n = blockIdx.x*256 + threadIdx.x;
  if (n >= MTOT) return;
  int m = (n & 127)*9 + (n >> 7);     // source column in z
  float s = 0.f;
  for (int c0 = 0; c0 < 256; c0 += 32){
    __align__(16) ushort_t buf[32];
#pragma unroll
    for (int i = 0; i < 32; ++i){
      float f = isb ? b2f(((const ushort_t*)zraw)[(size_t)(c0+i)*MTOT + m])
                    : ((const float*)zraw)[(size_t)(c0+i)*MTOT + m];
      buf[i] = f2b(f); s += f*f;
    }
    uint4* dst = (uint4*)(zT + (size_t)n*256 + c0);
#pragma unroll
    for (int q = 0; q < 4; ++q) dst[q] = *(uint4*)&buf[q*8];
  }
  float zn = fmaxf(sqrtf(s), 1e-15f);
  float rv = isb ? b2f(((const ushort_t*)rraw)[m]) : ((const float*)rraw)[m];
  float tc = 2.0f * rv;               // tcr = 2*sqrt(c)*r, c=1
  A1[n] = coshf(tc) / zn;
  B1[n] = sinhf(tc);
  S1[n] = 2.0f * zn;
}

// ------------- Kernel 2: GEMM + fast-asinh epilogue -> v (bf16), vn2 atomics -
__global__ __launch_bounds__(256) void k_gemm(const ushort_t* __restrict__ xT,
                                              const ushort_t* __restrict__ zT,
                                              const float* __restrict__ lam,
                                              const float* __restrict__ A1,
                                              const float* __restrict__ B1,
                                              const float* __restrict__ S1,
                                              ushort_t* __restrict__ vbuf,
                                              float* __restrict__ vn2){
  __shared__ __align__(16) ushort_t sh[16384];   // As/Bs; epilogue vtile reuse
  __shared__ float lamS[128], A1S[128], B1S[128], S1S[128];
  int t = threadIdx.x;
  int p0 = blockIdx.x * 128;
  int n0 = blockIdx.y * 128;
  if (t < 128){
    lamS[t] = lam[p0+t];
    A1S[t] = A1[n0+t]; B1S[t] = B1[n0+t]; S1S[t] = S1[n0+t];
  }
  int wave = t >> 6, lane = t & 63;
  int wr = wave >> 1, wc = wave & 1;
  f32x4 acc[4][4];
#pragma unroll
  for (int i=0;i<4;i++)
#pragma unroll
    for (int j=0;j<4;j++) acc[i][j] = (f32x4){0.f,0.f,0.f,0.f};

  for (int kt = 0; kt < 4; ++kt){
    int ci0 = kt*64;
    __syncthreads();
#pragma unroll
    for (int i = 0; i < 4; ++i){
      int c = i*256 + t;
      int p = c >> 3, ko = (c & 7)*8;
      *(uint4*)&sh[c*8] = *(const uint4*)(xT + (size_t)(p0+p)*256 + ci0 + ko);
    }
#pragma unroll
    for (int i = 0; i < 4; ++i){
      int c = i*256 + t;
      int mrow = c >> 3, ko = (c & 7)*8;
      *(uint4*)&sh[8192 + c*8] = *(const uint4*)(zT + (size_t)(n0+mrow)*256 + ci0 + ko);
    }
    __syncthreads();
#pragma unroll
    for (int ks = 0; ks < 2; ++ks){
      short8 av[4], bv[4];
      int koff = ks*32 + (lane>>4)*8;
#pragma unroll
      for (int rt = 0; rt < 4; ++rt){
        int row = wr*64 + rt*16 + (lane & 15);
        av[rt] = *(const short8*)&sh[row*64 + koff];
      }
#pragma unroll
      for (int ct = 0; ct < 4; ++ct){
        int mr = wc*64 + ct*16 + (lane & 15);
        bv[ct] = *(const short8*)&sh[8192 + mr*64 + koff];
      }
#pragma unroll
      for (int rt = 0; rt < 4; ++rt)
#pragma unroll
        for (int ct = 0; ct < 4; ++ct)
          acc[rt][ct] = __builtin_amdgcn_mfma_f32_16x16x32_bf16(av[rt], bv[ct], acc[rt][ct], 0, 0, 0);
    }
  }
  __syncthreads();
  // epilogue: v = S1 * asinh(lam*xz*A1 - (lam-1)*B1), fast asinh
#pragma unroll
  for (int rt = 0; rt < 4; ++rt){
#pragma unroll
    for (int ct = 0; ct < 4; ++ct){
#pragma unroll
      for (int rg = 0; rg < 4; ++rg){
        int row = wr*64 + rt*16 + (lane>>4)*4 + rg;
        int col = wc*64 + ct*16 + (lane & 15);
        float xz = acc[rt][ct][rg];
        float lm = lamS[row];
        float tv = lm * xz * A1S[col] - (lm - 1.0f) * B1S[col];
        float ax = fabsf(tv);
        float sq = sqrtf(fmaf(ax, ax, 1.0f));
        float lg = __log2f(ax + sq) * 0.69314718055994531f;  // asinh(|tv|)
        float v = S1S[col] * copysignf(lg, tv);
        sh[row*128 + col] = f2b(v);
      }
    }
  }
  __syncthreads();
  {
    // each thread flushes one 64-col half-row: 64 bf16 = 128 B = 8 uint4
    int row = t >> 1, half = t & 1;
    float s = 0.f;
    uint4 outv[8];
#pragma unroll
    for (int i = 0; i < 8; ++i){
      ushort_t* src = &sh[row*128 + half*64 + i*8];
      uint4 u = *(uint4*)src;
      outv[i] = u;
#pragma unroll
      for (int e = 0; e < 8; ++e){ float f = b2f(src[e]); s += f*f; }
    }
    uint4* dst = (uint4*)(vbuf + (size_t)(p0+row)*MTOT + n0 + half*64);
#pragma unroll
    for (int i = 0; i < 8; ++i) dst[i] = outv[i];
    atomicAdd(&vn2[p0+row], s);
  }
}

// ------------- Kernel 4: fused gather fold (inv, lam2, gyromidpoint, Mobius) -
__global__ __launch_bounds__(1024) void k_fold(const ushort_t* __restrict__ vbuf,
                                               const float* __restrict__ vn2,
                                               const float* __restrict__ flag,
                                               void* __restrict__ outraw){
  __shared__ ushort_t stg[128*32];
  int isb = (flag[0] != 0.0f);
  int t = threadIdx.x;
  int oy = blockIdx.y;
  int bz = blockIdx.z;
  int wv = t >> 6, l = t & 63, half = l >> 5, cl = l & 31;
  int ox = blockIdx.x*32 + wv*2 + half;
  int oxc = min(ox, 128);
  int khs[2], hs[2], kws[2], wxs[2];
  int ny = 0, nx = 0;
  if (oy & 1){ khs[0]=1; hs[0]=(oy-1)>>1; ny=1; }
  else {
    int h0 = oy>>1; if (h0 < 64){ khs[ny]=0; hs[ny]=h0; ny++; }
    if (oy >= 2){ khs[ny]=2; hs[ny]=(oy-2)>>1; ny++; }
  }
  if (oxc & 1){ kws[0]=1; wxs[0]=(oxc-1)>>1; nx=1; }
  else {
    int w0 = oxc>>1; if (w0 < 64){ kws[nx]=0; wxs[nx]=w0; nx++; }
    if (oxc >= 2){ kws[nx]=2; wxs[nx]=(oxc-2)>>1; nx++; }
  }
  float num[4] = {0,0,0,0};
  float dacc = 0.f;
  for (int iy = 0; iy < ny; ++iy){
    for (int ix = 0; ix < nx; ++ix){
      int pix = (bz<<12) + (hs[iy]<<6) + wxs[ix];
      int k = khs[iy]*3 + kws[ix];
      float iv = 1.0f / (1.0f + sqrtf(1.0f + vn2[pix]));   // ball map scale
      const ushort_t* bp = vbuf + (size_t)pix*MTOT + k*128;
      float w[4];
#pragma unroll
      for (int j = 0; j < 4; ++j) w[j] = b2f(bp[cl + 32*j]) * iv;
      float sq = w[0]*w[0] + w[1]*w[1] + w[2]*w[2] + w[3]*w[3];
#pragma unroll
      for (int d = 1; d < 32; d <<= 1) sq += __shfl_xor(sq, d, 64);
      float l2 = 2.0f / (1.0f - sq);                       // conformal factor
      dacc += l2 - 1.0f;
#pragma unroll
      for (int j = 0; j < 4; ++j) num[j] += l2 * w[j];
    }
  }
  float fr[4], fn2 = 0.f;
  float dinv = 1.0f / dacc;
#pragma unroll
  for (int j = 0; j < 4; ++j){ fr[j] = num[j]*dinv; fn2 += fr[j]*fr[j]; }
#pragma unroll
  for (int d = 1; d < 32; d <<= 1) fn2 += __shfl_xor(fn2, d, 32);
  float fn = sqrtf(fn2);
  float arg = fminf(fn, 1.0f - 1e-7f);
  // tanh(0.5*atanh(arg)) = arg/(1+sqrt(1-arg^2))
  float scale = arg / ((1.0f + sqrtf(1.0f - arg*arg)) * fmaxf(fn, 1e-15f));
  int oxl = wv*2 + half;
#pragma unroll
  for (int j = 0; j < 4; ++j) stg[(cl + 32*j)*32 + oxl] = f2b(fr[j]*scale);
  __syncthreads();
  int c = t >> 3, x4 = (t & 7)*4;
#pragma unroll
  for (int e = 0; e < 4; ++e){
    int oxw = blockIdx.x*32 + x4 + e;
    if (oxw < OHW){
      size_t off = (((size_t)bz*NCOUT + c)*OHW + oy)*OHW + oxw;
      if (isb) ((ushort_t*)outraw)[off] = stg[c*32 + x4 + e];
      else     ((float*)outraw)[off]    = b2f(stg[c*32 + x4 + e]);
    }
  }
}

// ------------- launch --------------------------------------------------------
extern "C" void kernel_launch(void* const* d_in, const int* in_sizes, int n_in,
                              void* d_out, int out_size, void* d_ws, size_t ws_size,
                              hipStream_t stream){
  const void* x = d_in[0];
  const void* z = d_in[1];
  const void* r = d_in[2];
  char* ws = (char*)d_ws;
  size_t off = 0;
  auto alloc = [&](size_t bytes)->char*{ char* p = ws + off; off += (bytes + 255) & ~(size_t)255; return p; };
  ushort_t* xT  = (ushort_t*)alloc((size_t)PIX*CIN*2);
  ushort_t* zT  = (ushort_t*)alloc((size_t)MTOT*CIN*2);
  float* lam    = (float*)alloc((size_t)PIX*4);
  float* vn2    = (float*)alloc((size_t)PIX*4);
  float* A1     = (float*)alloc(MTOT*4);
  float* B1     = (float*)alloc(MTOT*4);
  float* S1     = (float*)alloc(MTOT*4);
  ushort_t* vbuf= (ushort_t*)alloc((size_t)PIX*MTOT*2);
  float* flag   = (float*)alloc(256);
  (void)in_sizes; (void)n_in; (void)out_size; (void)ws_size;

  hipLaunchKernelGGL(k_detect,   dim3(1),       dim3(256),  0, stream, (const ushort_t*)x, flag);
  hipLaunchKernelGGL(k_prep_pix, dim3(256),     dim3(256),  0, stream, x, flag, xT, lam, vn2);
  hipLaunchKernelGGL(k_prep_col, dim3(5),       dim3(256),  0, stream, z, r, flag, zT, A1, B1, S1);
  hipLaunchKernelGGL(k_gemm,     dim3(256,9),   dim3(256),  0, stream, xT, zT, lam, A1, B1, S1, vbuf, vn2);
  hipLaunchKernelGGL(k_fold,     dim3(5,129,8), dim3(1024), 0, stream, vbuf, vn2, flag, d_out);
}

// Round 5
// 346.525 us; speedup vs baseline: 1.2466x; 1.0229x over previous
//
#include <hip/hip_runtime.h>
#include <stdint.h>

#define CIN 256
#define PIX 32768
#define MTOT 1152
#define NCOUT 128
#define OHW 129

typedef unsigned short ushort_t;
typedef __attribute__((ext_vector_type(8))) short short8;
typedef __attribute__((ext_vector_type(4))) float f32x4;

__device__ __forceinline__ float b2f(ushort_t u){
  union { unsigned int i; float f; } v; v.i = ((unsigned int)u) << 16; return v.f;
}
__device__ __forceinline__ ushort_t f2b(float f){
  union { float f; unsigned int i; } v; v.f = f;
  unsigned int i = v.i;
  unsigned int r = (i + 0x7FFFu + ((i >> 16) & 1u)) >> 16;
  return (ushort_t)r;
}

// ------------- Kernel D: detect input dtype (bf16 vs fp32) -------------------
__global__ __launch_bounds__(256) void k_detect(const ushort_t* __restrict__ x,
                                                float* __restrict__ flag){
  __shared__ float red[256];
  int t = threadIdx.x;
  float mx = 0.f;
  for (int i = t; i < 65536; i += 256){
    float f = fabsf(b2f(x[i]));
    if (!(f < 1e30f)) f = 1e30f;       // NaN/Inf patterns count as huge
    mx = fmaxf(mx, f);
  }
  red[t] = mx; __syncthreads();
  for (int s = 128; s > 0; s >>= 1){
    if (t < s) red[t] = fmaxf(red[t], red[t+s]);
    __syncthreads();
  }
  if (t == 0) flag[0] = (red[0] < 1e10f) ? 1.0f : 0.0f;  // 1 -> bf16
}

// ------------- Kernel 0: x -> xT[pix][ci] (bf16), lam[pix], zero vn2 ---------
__global__ __launch_bounds__(256) void k_prep_pix(const void* __restrict__ xraw,
                                                  const float* __restrict__ flag,
                                                  ushort_t* __restrict__ xT,
                                                  float* __restrict__ lam,
                                                  float* __restrict__ vn2){
  __shared__ float tile[64*129];
  __shared__ float ssum[256];
  int isb = (flag[0] != 0.0f);
  int t = threadIdx.x;
  int p0 = blockIdx.x * 128;
  int b = p0 >> 12;
  int hw0 = p0 & 4095;
  float s = 0.f;
  for (int ci0 = 0; ci0 < 256; ci0 += 64){
    __syncthreads();
    if (isb){
      const uint* xb32 = (const uint*)((const ushort_t*)xraw + ((size_t)b*CIN)*4096 + hw0);
#pragma unroll
      for (int i = 0; i < 16; ++i){
        int idx = i*256 + t;          // 0..4095 uint chunks
        int ch = idx >> 6;            // 0..63
        int pp = idx & 63;            // uint column
        uint u = xb32[(size_t)(ci0+ch)*2048 + pp];
        tile[ch*129 + pp*2]     = b2f((ushort_t)(u & 0xffffu));
        tile[ch*129 + pp*2 + 1] = b2f((ushort_t)(u >> 16));
      }
    } else {
      const float* xb = (const float*)xraw + ((size_t)b*CIN)*4096 + hw0;
#pragma unroll
      for (int i = 0; i < 32; ++i){
        int idx = i*256 + t;
        int ch = idx >> 7, p = idx & 127;
        tile[ch*129 + p] = xb[(size_t)(ci0+ch)*4096 + p];
      }
    }
    __syncthreads();
    int p = t & 127, cih = t >> 7;
    __align__(16) ushort_t buf[32];
#pragma unroll
    for (int i = 0; i < 32; ++i){
      float f = tile[(cih*32+i)*129 + p];
      buf[i] = f2b(f);
      s += f*f;
    }
    uint4* dst = (uint4*)(xT + (size_t)(p0+p)*256 + ci0 + cih*32);
#pragma unroll
    for (int q = 0; q < 4; ++q) dst[q] = *(uint4*)&buf[q*8];
  }
  ssum[t] = s;
  __syncthreads();
  if (t < 128){
    float n2 = ssum[t] + ssum[t+128];
    lam[p0+t] = 2.0f / (1.0f - n2);   // c = 1
    vn2[p0+t] = 0.f;
  }
}

// ------------- Kernel 1: PERMUTED zT[n][ci], per-column constants ------------
// column order n = k*128 + c  <->  reference m = c*9 + k
__global__ __launch_bounds__(256) void k_prep_col(const void* __restrict__ zraw,
                                                  const void* __restrict__ rraw,
                                                  const float* __restrict__ flag,
                                                  ushort_t* __restrict__ zT,
                                                  float* __restrict__ A1,
                                                  float* __restrict__ B1,
                                                  float* __restrict__ S1){
  int isb = (flag[0] != 0.0f);
  int n = blockIdx.x*256 + threadIdx.x;
  if (n >= MTOT) return;
  int m = (n & 127)*9 + (n >> 7);     // source column in z
  float s = 0.f;
  for (int c0 = 0; c0 < 256; c0 += 32){
    __align__(16) ushort_t buf[32];
#pragma unroll
    for (int i = 0; i < 32; ++i){
      float f = isb ? b2f(((const ushort_t*)zraw)[(size_t)(c0+i)*MTOT + m])
                    : ((const float*)zraw)[(size_t)(c0+i)*MTOT + m];
      buf[i] = f2b(f); s += f*f;
    }
    uint4* dst = (uint4*)(zT + (size_t)n*256 + c0);
#pragma unroll
    for (int q = 0; q < 4; ++q) dst[q] = *(uint4*)&buf[q*8];
  }
  float zn = fmaxf(sqrtf(s), 1e-15f);
  float rv = isb ? b2f(((const ushort_t*)rraw)[m]) : ((const float*)rraw)[m];
  float tc = 2.0f * rv;               // tcr = 2*sqrt(c)*r, c=1
  A1[n] = coshf(tc) / zn;
  B1[n] = sinhf(tc);
  S1[n] = 2.0f * zn;
}

// ------------- Kernel 2: swizzled-LDS GEMM + fast-asinh epilogue -------------
// LDS A/B tile: row = 128 B = 8 chunks of 16 B; chunk stored at (chunk ^ (row&7)).
// vtile: row = 256 B = 16 chunks; chunk stored at (chunk ^ (row&15)).
__global__ __launch_bounds__(256) void k_gemm(const ushort_t* __restrict__ xT,
                                              const ushort_t* __restrict__ zT,
                                              const float* __restrict__ lam,
                                              const float* __restrict__ A1,
                                              const float* __restrict__ B1,
                                              const float* __restrict__ S1,
                                              ushort_t* __restrict__ vbuf,
                                              float* __restrict__ vn2,
                                              float* __restrict__ sk){
  __shared__ __align__(16) ushort_t sh[16384];   // As [0,8192), Bs [8192,16384); vtile reuse
  __shared__ float lamS[128], A1S[128], B1S[128], S1S[128];
  __shared__ float sred[256];
  int t = threadIdx.x;
  int p0 = blockIdx.x * 128;
  int n0 = blockIdx.y;                 // == kernel-tap index k; col block = n0*128
  if (t < 128){
    lamS[t] = lam[p0+t];
    A1S[t] = A1[n0*128+t]; B1S[t] = B1[n0*128+t]; S1S[t] = S1[n0*128+t];
  }
  int wave = t >> 6, lane = t & 63;
  int wr = wave >> 1, wc = wave & 1;
  f32x4 acc[4][4];
#pragma unroll
  for (int i=0;i<4;i++)
#pragma unroll
    for (int j=0;j<4;j++) acc[i][j] = (f32x4){0.f,0.f,0.f,0.f};

  for (int kt = 0; kt < 4; ++kt){
    int ci0 = kt*64;
    __syncthreads();   // previous MFMA reads done before overwrite
    // async staging, swizzle folded into per-lane SOURCE address
#pragma unroll
    for (int i = 0; i < 4; ++i){
      int sbase = wave*256 + i*64;        // wave-uniform slot base
      int slot = sbase + lane;
      int row = slot >> 3, jj = slot & 7;
      int j = jj ^ (row & 7);             // source chunk for this LDS slot
      const ushort_t* g = xT + (size_t)(p0+row)*256 + ci0 + j*8;
      __builtin_amdgcn_global_load_lds((const __attribute__((address_space(1))) void*)g,
                                       (__attribute__((address_space(3))) void*)&sh[sbase*8],
                                       16, 0, 0);
    }
#pragma unroll
    for (int i = 0; i < 4; ++i){
      int sbase = wave*256 + i*64;
      int slot = sbase + lane;
      int row = slot >> 3, jj = slot & 7;
      int j = jj ^ (row & 7);
      const ushort_t* g = zT + (size_t)(n0*128+row)*256 + ci0 + j*8;
      __builtin_amdgcn_global_load_lds((const __attribute__((address_space(1))) void*)g,
                                       (__attribute__((address_space(3))) void*)&sh[8192 + sbase*8],
                                       16, 0, 0);
    }
    __syncthreads();   // drain DMA before reading
#pragma unroll
    for (int ks = 0; ks < 2; ++ks){
      short8 av[4], bv[4];
      int jbase = ks*4 + (lane>>4);       // logical chunk for this lane quad
#pragma unroll
      for (int rt = 0; rt < 4; ++rt){
        int row = wr*64 + rt*16 + (lane & 15);
        av[rt] = *(const short8*)&sh[row*64 + ((jbase ^ (row & 7))*8)];
      }
#pragma unroll
      for (int ct = 0; ct < 4; ++ct){
        int mr = wc*64 + ct*16 + (lane & 15);
        bv[ct] = *(const short8*)&sh[8192 + mr*64 + ((jbase ^ (mr & 7))*8)];
      }
#pragma unroll
      for (int rt = 0; rt < 4; ++rt)
#pragma unroll
        for (int ct = 0; ct < 4; ++ct)
          acc[rt][ct] = __builtin_amdgcn_mfma_f32_16x16x32_bf16(av[rt], bv[ct], acc[rt][ct], 0, 0, 0);
    }
  }
  __syncthreads();     // all MFMA LDS reads done before vtile overwrite
  // epilogue: v = S1 * asinh(lam*xz*A1 - (lam-1)*B1), fast asinh; swizzled vtile
#pragma unroll
  for (int rt = 0; rt < 4; ++rt){
#pragma unroll
    for (int ct = 0; ct < 4; ++ct){
#pragma unroll
      for (int rg = 0; rg < 4; ++rg){
        int row = wr*64 + rt*16 + (lane>>4)*4 + rg;
        int col = wc*64 + ct*16 + (lane & 15);
        float xz = acc[rt][ct][rg];
        float lm = lamS[row];
        float tv = lm * xz * A1S[col] - (lm - 1.0f) * B1S[col];
        float ax = fabsf(tv);
        float sq = sqrtf(fmaf(ax, ax, 1.0f));
        float lg = __log2f(ax + sq) * 0.69314718055994531f;  // asinh(|tv|)
        float v = S1S[col] * copysignf(lg, tv);
        sh[row*128 + (((col>>3) ^ (row & 15))*8 + (col & 7))] = f2b(v);
      }
    }
  }
  __syncthreads();
  {
    // flush one 64-col half-row per thread (8 chunks, un-swizzling on read)
    int row = t >> 1, half = t & 1;
    float s = 0.f;
    uint4 outv[8];
#pragma unroll
    for (int i = 0; i < 8; ++i){
      int c = half*8 + i;                       // logical chunk
      ushort_t* src = &sh[row*128 + ((c ^ (row & 15))*8)];
      uint4 u = *(uint4*)src;
      outv[i] = u;
#pragma unroll
      for (int e = 0; e < 8; ++e){ float f = b2f(src[e]); s += f*f; }
    }
    uint4* dst = (uint4*)(vbuf + (size_t)(p0+row)*MTOT + n0*128 + half*64);
#pragma unroll
    for (int i = 0; i < 8; ++i) dst[i] = outv[i];
    sred[t] = s;
  }
  __syncthreads();
  if (t < 128){
    float stot = sred[2*t] + sred[2*t+1];       // full-row sum for this k-tile
    atomicAdd(&vn2[p0+t], stot);
    sk[(size_t)(p0+t)*9 + n0] = stot;
  }
}

// ------------- Kernel 4: gather fold — scalar l2 via sk, no per-tap reduce ---
__global__ __launch_bounds__(1024) void k_fold(const ushort_t* __restrict__ vbuf,
                                               const float* __restrict__ vn2,
                                               const float* __restrict__ sk,
                                               const float* __restrict__ flag,
                                               void* __restrict__ outraw){
  __shared__ ushort_t stg[128*32];
  int isb = (flag[0] != 0.0f);
  int t = threadIdx.x;
  int oy = blockIdx.y;
  int bz = blockIdx.z;
  int wv = t >> 6, l = t & 63, half = l >> 5, cl = l & 31;
  int ox = blockIdx.x*32 + wv*2 + half;
  int oxc = min(ox, 128);
  int khs[2], hs[2], kws[2], wxs[2];
  int ny = 0, nx = 0;
  if (oy & 1){ khs[0]=1; hs[0]=(oy-1)>>1; ny=1; }
  else {
    int h0 = oy>>1; if (h0 < 64){ khs[ny]=0; hs[ny]=h0; ny++; }
    if (oy >= 2){ khs[ny]=2; hs[ny]=(oy-2)>>1; ny++; }
  }
  if (oxc & 1){ kws[0]=1; wxs[0]=(oxc-1)>>1; nx=1; }
  else {
    int w0 = oxc>>1; if (w0 < 64){ kws[nx]=0; wxs[nx]=w0; nx++; }
    if (oxc >= 2){ kws[nx]=2; wxs[nx]=(oxc-2)>>1; nx++; }
  }
  float num[4] = {0,0,0,0};
  float dacc = 0.f;
  for (int iy = 0; iy < ny; ++iy){
    for (int ix = 0; ix < nx; ++ix){
      int pix = (bz<<12) + (hs[iy]<<6) + wxs[ix];
      int k = khs[iy]*3 + kws[ix];
      float vn  = vn2[pix];
      float skv = sk[(size_t)pix*9 + k];
      float iv  = 1.0f / (1.0f + sqrtf(1.0f + vn));     // ball map scale
      float l2  = 2.0f / (1.0f - iv*iv*skv);            // conformal factor
      dacc += l2 - 1.0f;
      float sc = l2 * iv;
      const ushort_t* bp = vbuf + (size_t)pix*MTOT + k*128;
#pragma unroll
      for (int j = 0; j < 4; ++j) num[j] += sc * b2f(bp[cl + 32*j]);
    }
  }
  float fr[4], fn2 = 0.f;
  float dinv = 1.0f / dacc;
#pragma unroll
  for (int j = 0; j < 4; ++j){ fr[j] = num[j]*dinv; fn2 += fr[j]*fr[j]; }
#pragma unroll
  for (int d = 1; d < 32; d <<= 1) fn2 += __shfl_xor(fn2, d, 32);
  float fn = sqrtf(fn2);
  float arg = fminf(fn, 1.0f - 1e-7f);
  // tanh(0.5*atanh(arg)) = arg/(1+sqrt(1-arg^2))
  float scale = arg / ((1.0f + sqrtf(1.0f - arg*arg)) * fmaxf(fn, 1e-15f));
  int oxl = wv*2 + half;
#pragma unroll
  for (int j = 0; j < 4; ++j) stg[(cl + 32*j)*32 + oxl] = f2b(fr[j]*scale);
  __syncthreads();
  int c = t >> 3, x4 = (t & 7)*4;
#pragma unroll
  for (int e = 0; e < 4; ++e){
    int oxw = blockIdx.x*32 + x4 + e;
    if (oxw < OHW){
      size_t off = (((size_t)bz*NCOUT + c)*OHW + oy)*OHW + oxw;
      if (isb) ((ushort_t*)outraw)[off] = stg[c*32 + x4 + e];
      else     ((float*)outraw)[off]    = b2f(stg[c*32 + x4 + e]);
    }
  }
}

// ------------- launch --------------------------------------------------------
extern "C" void kernel_launch(void* const* d_in, const int* in_sizes, int n_in,
                              void* d_out, int out_size, void* d_ws, size_t ws_size,
                              hipStream_t stream){
  const void* x = d_in[0];
  const void* z = d_in[1];
  const void* r = d_in[2];
  char* ws = (char*)d_ws;
  size_t off = 0;
  auto alloc = [&](size_t bytes)->char*{ char* p = ws + off; off += (bytes + 255) & ~(size_t)255; return p; };
  ushort_t* xT  = (ushort_t*)alloc((size_t)PIX*CIN*2);
  ushort_t* zT  = (ushort_t*)alloc((size_t)MTOT*CIN*2);
  float* lam    = (float*)alloc((size_t)PIX*4);
  float* vn2    = (float*)alloc((size_t)PIX*4);
  float* A1     = (float*)alloc(MTOT*4);
  float* B1     = (float*)alloc(MTOT*4);
  float* S1     = (float*)alloc(MTOT*4);
  ushort_t* vbuf= (ushort_t*)alloc((size_t)PIX*MTOT*2);
  float* sk     = (float*)alloc((size_t)PIX*9*4);
  float* flag   = (float*)alloc(256);
  (void)in_sizes; (void)n_in; (void)out_size; (void)ws_size;

  hipLaunchKernelGGL(k_detect,   dim3(1),       dim3(256),  0, stream, (const ushort_t*)x, flag);
  hipLaunchKernelGGL(k_prep_pix, dim3(256),     dim3(256),  0, stream, x, flag, xT, lam, vn2);
  hipLaunchKernelGGL(k_prep_col, dim3(5),       dim3(256),  0, stream, z, r, flag, zT, A1, B1, S1);
  hipLaunchKernelGGL(k_gemm,     dim3(256,9),   dim3(256),  0, stream, xT, zT, lam, A1, B1, S1, vbuf, vn2, sk);
  hipLaunchKernelGGL(k_fold,     dim3(5,129,8), dim3(1024), 0, stream, vbuf, vn2, sk, flag, d_out);
}

// Round 6
// 313.854 us; speedup vs baseline: 1.3764x; 1.1041x over previous
//
#include <hip/hip_runtime.h>
#include <stdint.h>

#define CIN 256
#define PIX 32768
#define MTOT 1152
#define NCOUT 128
#define OHW 129

typedef unsigned short ushort_t;
typedef __attribute__((ext_vector_type(8))) short short8;
typedef __attribute__((ext_vector_type(4))) float f32x4;

__device__ __forceinline__ float b2f(ushort_t u){
  union { unsigned int i; float f; } v; v.i = ((unsigned int)u) << 16; return v.f;
}
__device__ __forceinline__ ushort_t f2b(float f){
  union { float f; unsigned int i; } v; v.f = f;
  unsigned int i = v.i;
  unsigned int r = (i + 0x7FFFu + ((i >> 16) & 1u)) >> 16;
  return (ushort_t)r;
}

// ------------- Kernel D: detect input dtype (bf16 vs fp32) -------------------
__global__ __launch_bounds__(256) void k_detect(const ushort_t* __restrict__ x,
                                                float* __restrict__ flag){
  __shared__ float red[256];
  int t = threadIdx.x;
  float mx = 0.f;
  for (int i = t; i < 8192; i += 256){
    float f = fabsf(b2f(x[i]));
    if (!(f < 1e30f)) f = 1e30f;       // NaN/Inf patterns count as huge
    mx = fmaxf(mx, f);
  }
  red[t] = mx; __syncthreads();
  for (int s = 128; s > 0; s >>= 1){
    if (t < s) red[t] = fmaxf(red[t], red[t+s]);
    __syncthreads();
  }
  if (t == 0) flag[0] = (red[0] < 1e10f) ? 1.0f : 0.0f;  // 1 -> bf16
}

// ------------- Kernel 0: x -> xT[pix][ci] (bf16), lam[pix], zero vn2 ---------
__global__ __launch_bounds__(256) void k_prep_pix(const void* __restrict__ xraw,
                                                  const float* __restrict__ flag,
                                                  ushort_t* __restrict__ xT,
                                                  float* __restrict__ lam,
                                                  float* __restrict__ vn2){
  __shared__ float tile[64*129];
  __shared__ float ssum[256];
  int isb = (flag[0] != 0.0f);
  int t = threadIdx.x;
  int p0 = blockIdx.x * 128;
  int b = p0 >> 12;
  int hw0 = p0 & 4095;
  float s = 0.f;
  for (int ci0 = 0; ci0 < 256; ci0 += 64){
    __syncthreads();
    if (isb){
      const uint* xb32 = (const uint*)((const ushort_t*)xraw + ((size_t)b*CIN)*4096 + hw0);
#pragma unroll
      for (int i = 0; i < 16; ++i){
        int idx = i*256 + t;          // 0..4095 uint chunks
        int ch = idx >> 6;            // 0..63
        int pp = idx & 63;            // uint column
        uint u = xb32[(size_t)(ci0+ch)*2048 + pp];
        tile[ch*129 + pp*2]     = b2f((ushort_t)(u & 0xffffu));
        tile[ch*129 + pp*2 + 1] = b2f((ushort_t)(u >> 16));
      }
    } else {
      const float* xb = (const float*)xraw + ((size_t)b*CIN)*4096 + hw0;
#pragma unroll
      for (int i = 0; i < 32; ++i){
        int idx = i*256 + t;
        int ch = idx >> 7, p = idx & 127;
        tile[ch*129 + p] = xb[(size_t)(ci0+ch)*4096 + p];
      }
    }
    __syncthreads();
    int p = t & 127, cih = t >> 7;
    __align__(16) ushort_t buf[32];
#pragma unroll
    for (int i = 0; i < 32; ++i){
      float f = tile[(cih*32+i)*129 + p];
      buf[i] = f2b(f);
      s += f*f;
    }
    uint4* dst = (uint4*)(xT + (size_t)(p0+p)*256 + ci0 + cih*32);
#pragma unroll
    for (int q = 0; q < 4; ++q) dst[q] = *(uint4*)&buf[q*8];
  }
  ssum[t] = s;
  __syncthreads();
  if (t < 128){
    float n2 = ssum[t] + ssum[t+128];
    lam[p0+t] = 2.0f / (1.0f - n2);   // c = 1
    vn2[p0+t] = 0.f;
  }
}

// ------------- Kernel 1: PERMUTED zT[n][ci] via LDS transpose, 9 blocks ------
// column order n = k*128 + c  <->  reference m = c*9 + k;  block = one k
__global__ __launch_bounds__(256) void k_prep_col(const void* __restrict__ zraw,
                                                  const void* __restrict__ rraw,
                                                  const float* __restrict__ flag,
                                                  ushort_t* __restrict__ zT,
                                                  float* __restrict__ A1,
                                                  float* __restrict__ B1,
                                                  float* __restrict__ S1){
  __shared__ float tile[64*129];
  __shared__ float red[256];
  int isb = (flag[0] != 0.0f);
  int t = threadIdx.x;
  int k = blockIdx.x;                  // tap 0..8
  float s = 0.f;                       // per-thread norm partial for c = t&127
  int c = t & 127, half = t >> 7;
  for (int cich = 0; cich < 4; ++cich){
    __syncthreads();
    // load 64 ci-rows, gather column m = c*9 + k
#pragma unroll
    for (int i = 0; i < 32; ++i){
      int slot = i*256 + t;            // 0..8191
      int cip = slot >> 7;             // 0..63
      int cc = slot & 127;             // == t&127 since 256%128==0
      size_t src = (size_t)(cich*64 + cip)*MTOT + cc*9 + k;
      float f = isb ? b2f(((const ushort_t*)zraw)[src]) : ((const float*)zraw)[src];
      tile[cip*129 + cc] = f;
      s += f*f;                        // cc == c for this thread
    }
    __syncthreads();
    // write zT[n = k*128+c][ci chunk]: 32 ci per half
    __align__(16) ushort_t buf[32];
#pragma unroll
    for (int i = 0; i < 32; ++i) buf[i] = f2b(tile[(half*32+i)*129 + c]);
    uint4* dst = (uint4*)(zT + (size_t)(k*128+c)*256 + cich*64 + half*32);
#pragma unroll
    for (int q = 0; q < 4; ++q) dst[q] = *(uint4*)&buf[q*8];
  }
  red[t] = s;
  __syncthreads();
  if (t < 128){
    int n = k*128 + t;
    int m = t*9 + k;
    float zn = fmaxf(sqrtf(red[t] + red[t+128]), 1e-15f);
    float rv = isb ? b2f(((const ushort_t*)rraw)[m]) : ((const float*)rraw)[m];
    float tc = 2.0f * rv;              // tcr = 2*sqrt(c)*r, c=1
    A1[n] = coshf(tc) / zn;
    B1[n] = sinhf(tc);
    S1[n] = 2.0f * zn;
  }
}

// ------------- Kernel 2: swizzled-LDS GEMM + fast-asinh epilogue -------------
__global__ __launch_bounds__(256) void k_gemm(const ushort_t* __restrict__ xT,
                                              const ushort_t* __restrict__ zT,
                                              const float* __restrict__ lam,
                                              const float* __restrict__ A1,
                                              const float* __restrict__ B1,
                                              const float* __restrict__ S1,
                                              ushort_t* __restrict__ vbuf,
                                              float* __restrict__ vn2,
                                              float* __restrict__ sk){
  __shared__ __align__(16) ushort_t sh[16384];   // As [0,8192), Bs [8192,16384); vtile reuse
  __shared__ float lamS[128], A1S[128], B1S[128], S1S[128];
  int t = threadIdx.x;
  int p0 = blockIdx.x * 128;
  int n0 = blockIdx.y;                 // tap index k; col block = n0*128
  if (t < 128){
    lamS[t] = lam[p0+t];
    A1S[t] = A1[n0*128+t]; B1S[t] = B1[n0*128+t]; S1S[t] = S1[n0*128+t];
  }
  int wave = t >> 6, lane = t & 63;
  int wr = wave >> 1, wc = wave & 1;
  f32x4 acc[4][4];
#pragma unroll
  for (int i=0;i<4;i++)
#pragma unroll
    for (int j=0;j<4;j++) acc[i][j] = (f32x4){0.f,0.f,0.f,0.f};

  for (int kt = 0; kt < 4; ++kt){
    int ci0 = kt*64;
    __syncthreads();
#pragma unroll
    for (int i = 0; i < 4; ++i){
      int sbase = wave*256 + i*64;
      int slot = sbase + lane;
      int row = slot >> 3, jj = slot & 7;
      int j = jj ^ (row & 7);
      const ushort_t* g = xT + (size_t)(p0+row)*256 + ci0 + j*8;
      __builtin_amdgcn_global_load_lds((const __attribute__((address_space(1))) void*)g,
                                       (__attribute__((address_space(3))) void*)&sh[sbase*8],
                                       16, 0, 0);
    }
#pragma unroll
    for (int i = 0; i < 4; ++i){
      int sbase = wave*256 + i*64;
      int slot = sbase + lane;
      int row = slot >> 3, jj = slot & 7;
      int j = jj ^ (row & 7);
      const ushort_t* g = zT + (size_t)(n0*128+row)*256 + ci0 + j*8;
      __builtin_amdgcn_global_load_lds((const __attribute__((address_space(1))) void*)g,
                                       (__attribute__((address_space(3))) void*)&sh[8192 + sbase*8],
                                       16, 0, 0);
    }
    __syncthreads();
#pragma unroll
    for (int ks = 0; ks < 2; ++ks){
      short8 av[4], bv[4];
      int jbase = ks*4 + (lane>>4);
#pragma unroll
      for (int rt = 0; rt < 4; ++rt){
        int row = wr*64 + rt*16 + (lane & 15);
        av[rt] = *(const short8*)&sh[row*64 + ((jbase ^ (row & 7))*8)];
      }
#pragma unroll
      for (int ct = 0; ct < 4; ++ct){
        int mr = wc*64 + ct*16 + (lane & 15);
        bv[ct] = *(const short8*)&sh[8192 + mr*64 + ((jbase ^ (mr & 7))*8)];
      }
#pragma unroll
      for (int rt = 0; rt < 4; ++rt)
#pragma unroll
        for (int ct = 0; ct < 4; ++ct)
          acc[rt][ct] = __builtin_amdgcn_mfma_f32_16x16x32_bf16(av[rt], bv[ct], acc[rt][ct], 0, 0, 0);
    }
  }
  __syncthreads();
  // epilogue: v = S1 * asinh(lam*xz*A1 - (lam-1)*B1); swizzled vtile (row=16 chunks)
#pragma unroll
  for (int rt = 0; rt < 4; ++rt){
#pragma unroll
    for (int ct = 0; ct < 4; ++ct){
#pragma unroll
      for (int rg = 0; rg < 4; ++rg){
        int row = wr*64 + rt*16 + (lane>>4)*4 + rg;
        int col = wc*64 + ct*16 + (lane & 15);
        float xz = acc[rt][ct][rg];
        float lm = lamS[row];
        float tv = lm * xz * A1S[col] - (lm - 1.0f) * B1S[col];
        float ax = fabsf(tv);
        float sq = sqrtf(fmaf(ax, ax, 1.0f));
        float lg = __log2f(ax + sq) * 0.69314718055994531f;  // asinh(|tv|)
        float v = S1S[col] * copysignf(lg, tv);
        sh[row*128 + (((col>>3) ^ (row & 15))*8 + (col & 7))] = f2b(v);
      }
    }
  }
  __syncthreads();
  {
    int row = t >> 1, half = t & 1;
    float s = 0.f;
    uint4 outv[8];
#pragma unroll
    for (int i = 0; i < 8; ++i){
      int c = half*8 + i;
      ushort_t* src = &sh[row*128 + ((c ^ (row & 15))*8)];
      uint4 u = *(uint4*)src;
      outv[i] = u;
#pragma unroll
      for (int e = 0; e < 8; ++e){ float f = b2f(src[e]); s += f*f; }
    }
    uint4* dst = (uint4*)(vbuf + (size_t)(p0+row)*MTOT + n0*128 + half*64);
#pragma unroll
    for (int i = 0; i < 8; ++i) dst[i] = outv[i];
    float s2 = s + __shfl_xor(s, 1, 64);         // combine the two halves
    if (half == 0){
      atomicAdd(&vn2[p0+row], s2);
      sk[(size_t)(p0+row)*9 + n0] = s2;
    }
  }
}

// ------------- Kernel 4: gather fold — wave per output pixel, uint loads -----
__global__ __launch_bounds__(1024) void k_fold(const ushort_t* __restrict__ vbuf,
                                               const float* __restrict__ vn2,
                                               const float* __restrict__ sk,
                                               const float* __restrict__ flag,
                                               void* __restrict__ outraw){
  __shared__ ushort_t stg[128*16];
  int isb = (flag[0] != 0.0f);
  int t = threadIdx.x;
  int oy = blockIdx.y;
  int bz = blockIdx.z;
  int wv = t >> 6, l = t & 63;
  int ox = blockIdx.x*16 + wv;
  int oxc = min(ox, 128);
  int khs[2], hs[2], kws[2], wxs[2];
  int ny = 0, nx = 0;
  if (oy & 1){ khs[0]=1; hs[0]=(oy-1)>>1; ny=1; }
  else {
    int h0 = oy>>1; if (h0 < 64){ khs[ny]=0; hs[ny]=h0; ny++; }
    if (oy >= 2){ khs[ny]=2; hs[ny]=(oy-2)>>1; ny++; }
  }
  if (oxc & 1){ kws[0]=1; wxs[0]=(oxc-1)>>1; nx=1; }
  else {
    int w0 = oxc>>1; if (w0 < 64){ kws[nx]=0; wxs[nx]=w0; nx++; }
    if (oxc >= 2){ kws[nx]=2; wxs[nx]=(oxc-2)>>1; nx++; }
  }
  float num0 = 0.f, num1 = 0.f, dacc = 0.f;
  for (int iy = 0; iy < ny; ++iy){
    for (int ix = 0; ix < nx; ++ix){
      int pix = (bz<<12) + (hs[iy]<<6) + wxs[ix];
      int k = khs[iy]*3 + kws[ix];
      float vn  = vn2[pix];
      float skv = sk[(size_t)pix*9 + k];
      float iv  = 1.0f / (1.0f + sqrtf(1.0f + vn));     // ball map scale
      float l2  = 2.0f / (1.0f - iv*iv*skv);            // conformal factor
      dacc += l2 - 1.0f;
      float scn = l2 * iv;
      uint u = *(const uint*)(vbuf + (size_t)pix*MTOT + k*128 + 2*l);
      num0 = fmaf(scn, b2f((ushort_t)(u & 0xffffu)), num0);
      num1 = fmaf(scn, b2f((ushort_t)(u >> 16)), num1);
    }
  }
  float dinv = 1.0f / dacc;
  float fr0 = num0*dinv, fr1 = num1*dinv;
  float fn2 = fr0*fr0 + fr1*fr1;
#pragma unroll
  for (int d = 1; d < 64; d <<= 1) fn2 += __shfl_xor(fn2, d, 64);
  float fn = sqrtf(fn2);
  float arg = fminf(fn, 1.0f - 1e-7f);
  // tanh(0.5*atanh(arg)) = arg/(1+sqrt(1-arg^2))
  float scale = arg / ((1.0f + sqrtf(1.0f - arg*arg)) * fmaxf(fn, 1e-15f));
  stg[(2*l)*16 + wv]   = f2b(fr0*scale);
  stg[(2*l+1)*16 + wv] = f2b(fr1*scale);
  __syncthreads();
  int c = t >> 3, x2 = (t & 7)*2;
#pragma unroll
  for (int e = 0; e < 2; ++e){
    int oxw = blockIdx.x*16 + x2 + e;
    if (oxw < OHW){
      size_t off = (((size_t)bz*NCOUT + c)*OHW + oy)*OHW + oxw;
      if (isb) ((ushort_t*)outraw)[off] = stg[c*16 + x2 + e];
      else     ((float*)outraw)[off]    = b2f(stg[c*16 + x2 + e]);
    }
  }
}

// ------------- launch --------------------------------------------------------
extern "C" void kernel_launch(void* const* d_in, const int* in_sizes, int n_in,
                              void* d_out, int out_size, void* d_ws, size_t ws_size,
                              hipStream_t stream){
  const void* x = d_in[0];
  const void* z = d_in[1];
  const void* r = d_in[2];
  char* ws = (char*)d_ws;
  size_t off = 0;
  auto alloc = [&](size_t bytes)->char*{ char* p = ws + off; off += (bytes + 255) & ~(size_t)255; return p; };
  ushort_t* xT  = (ushort_t*)alloc((size_t)PIX*CIN*2);
  ushort_t* zT  = (ushort_t*)alloc((size_t)MTOT*CIN*2);
  float* lam    = (float*)alloc((size_t)PIX*4);
  float* vn2    = (float*)alloc((size_t)PIX*4);
  float* A1     = (float*)alloc(MTOT*4);
  float* B1     = (float*)alloc(MTOT*4);
  float* S1     = (float*)alloc(MTOT*4);
  ushort_t* vbuf= (ushort_t*)alloc((size_t)PIX*MTOT*2);
  float* sk     = (float*)alloc((size_t)PIX*9*4);
  float* flag   = (float*)alloc(256);
  (void)in_sizes; (void)n_in; (void)out_size; (void)ws_size;

  hipLaunchKernelGGL(k_detect,   dim3(1),       dim3(256),  0, stream, (const ushort_t*)x, flag);
  hipLaunchKernelGGL(k_prep_pix, dim3(256),     dim3(256),  0, stream, x, flag, xT, lam, vn2);
  hipLaunchKernelGGL(k_prep_col, dim3(9),       dim3(256),  0, stream, z, r, flag, zT, A1, B1, S1);
  hipLaunchKernelGGL(k_gemm,     dim3(256,9),   dim3(256),  0, stream, xT, zT, lam, A1, B1, S1, vbuf, vn2, sk);
  hipLaunchKernelGGL(k_fold,     dim3(9,129,8), dim3(1024), 0, stream, vbuf, vn2, sk, flag, d_out);
}